// Round 6
// baseline (289.847 us; speedup 1.0000x reference)
//
#include <hip/hip_runtime.h>

// Problem constants
constexpr int N = 4096;   // nodes
constexpr int E = 4096;   // hyperedges
constexpr int F = 128;

// K-split: each block covers 256 k; grid (4096/64, KSPLIT); atomics combine.
constexpr int KSPLIT = 16;
constexpr int KEXT   = 4096 / KSPLIT;   // 256 k per block
constexpr int BK     = 64;              // k per chunk
constexpr int NCH    = KEXT / BK;       // 4 chunks

typedef __attribute__((ext_vector_type(8))) short bf16x8;
typedef __attribute__((ext_vector_type(4))) float f32x4;

__device__ __forceinline__ ushort f2bf_rne(float x) {
    union { float f; unsigned u; } v; v.f = x;
    return (ushort)((v.u + 0x7FFFu + ((v.u >> 16) & 1u)) >> 16);
}
// H is exactly {0,1}: truncation is exact.
__device__ __forceinline__ short f2bf_trunc(float x) {
    return (short)(ushort)(__float_as_uint(x) >> 16);
}

// ---------------------------------------------------------------------------
// reciprocal of the diagonals of D_v / D_e
// ---------------------------------------------------------------------------
__global__ void k_recip_diag(const float* __restrict__ Dv,
                             const float* __restrict__ De,
                             float* __restrict__ dv_inv,
                             float* __restrict__ de_inv) {
    int i = blockIdx.x * blockDim.x + threadIdx.x;
    if (i < N) dv_inv[i] = 1.0f / Dv[(size_t)i * (N + 1)];
    if (i < E) de_inv[i] = 1.0f / De[(size_t)i * (E + 1)];
}

// ---------------------------------------------------------------------------
// thetaT[f][n] = bf16( (X@W)[n][f] )   — [128][4096] bf16
// ---------------------------------------------------------------------------
__global__ void k_theta_t(const float* __restrict__ X,
                          const float* __restrict__ W,
                          ushort* __restrict__ thetaT) {
    __shared__ float Xs[8][F];
    const int r0 = blockIdx.x * 8;
    const int t  = threadIdx.x;  // 0..127 = f
    #pragma unroll
    for (int i = 0; i < 8; ++i)
        Xs[i][t] = X[(size_t)(r0 + i) * F + t];
    __syncthreads();
    float acc[8];
    #pragma unroll
    for (int i = 0; i < 8; ++i) acc[i] = 0.0f;
    for (int k = 0; k < F; ++k) {
        const float w = W[k * F + t];
        #pragma unroll
        for (int i = 0; i < 8; ++i) acc[i] += Xs[i][k] * w;
    }
    ushort u[8];
    #pragma unroll
    for (int i = 0; i < 8; ++i) u[i] = f2bf_rne(acc[i]);
    *(uint4*)&thetaT[(size_t)t * N + r0] = *(uint4*)u;
}

// ---------------------------------------------------------------------------
// GEMM1': MT[f][e] (+)= de_inv[e] * sum_n thetaT[f][n] * H[n][e]
//   No LDS, no barriers. A-frag (H^T cols) = 8 scalar dword loads (lanes
//   mm=0..15 coalesce to 64-B lines); B-frag (thetaT) = 16-B vector loads
//   (L2-resident). All deps register-carried -> compiler fine-grained vmcnt.
// Grid (E/64, KSPLIT); 256 thr = 4 waves; wave -> 16 e-cols x 128 f-rows.
// ---------------------------------------------------------------------------
__global__ __launch_bounds__(256, 4) void k_gemm1(
        const float* __restrict__ Hg,        // [N][E] fp32
        const ushort* __restrict__ thT,      // [F][N] bf16
        const float* __restrict__ de_inv,    // [E]
        float* __restrict__ MTf) {           // [F][E] fp32 (atomic)
    const int t    = threadIdx.x;
    const int wave = t >> 6;
    const int lane = t & 63;
    const int mm   = lane & 15;
    const int quad = lane >> 4;
    const int ew   = blockIdx.x * 64 + wave * 16;   // wave's 16 e-columns
    const int kb   = blockIdx.y * KEXT;

    f32x4 acc[8];
    #pragma unroll
    for (int ft = 0; ft < 8; ++ft) acc[ft] = (f32x4){0.f, 0.f, 0.f, 0.f};

    const float* hcol = Hg + ew + mm;               // this lane's e-column

    for (int ch = 0; ch < NCH; ++ch) {
        const int kg = kb + ch * BK;
        // H^T fragments: hb[kk][j] = H[kg + kk*32 + quad*8 + j][ew+mm]
        float hv[2][8];
        #pragma unroll
        for (int kk = 0; kk < 2; ++kk) {
            const int nbase = kg + kk * 32 + quad * 8;
            #pragma unroll
            for (int j = 0; j < 8; ++j)
                hv[kk][j] = hcol[(size_t)(nbase + j) * E];
        }
        // thetaT fragments (both kk) — issue all loads, then convert+MFMA
        bf16x8 af[2][8];
        #pragma unroll
        for (int kk = 0; kk < 2; ++kk) {
            const int ko = kg + kk * 32 + quad * 8;
            #pragma unroll
            for (int ft = 0; ft < 8; ++ft)
                af[kk][ft] = *(const bf16x8*)&thT[(size_t)(ft * 16 + mm) * N + ko];
        }
        #pragma unroll
        for (int kk = 0; kk < 2; ++kk) {
            bf16x8 hb;
            #pragma unroll
            for (int j = 0; j < 8; ++j) hb[j] = f2bf_trunc(hv[kk][j]);
            #pragma unroll
            for (int ft = 0; ft < 8; ++ft)
                acc[ft] = __builtin_amdgcn_mfma_f32_16x16x32_bf16(
                              af[kk][ft], hb, acc[ft], 0, 0, 0);
        }
    }
    // Epilogue: D row = f (ft*16 + quad*4 + r), col = e (mm); scale de_inv[e]
    const float s = de_inv[ew + mm];
    #pragma unroll
    for (int ft = 0; ft < 8; ++ft) {
        const int row = ft * 16 + quad * 4;
        #pragma unroll
        for (int r = 0; r < 4; ++r)
            atomicAdd(&MTf[(size_t)(row + r) * E + ew + mm], acc[ft][r] * s);
    }
}

// ---------------------------------------------------------------------------
// streaming cast: MTb[f][e] = bf16(MTf[f][e])
// ---------------------------------------------------------------------------
__global__ void k_castMT(const float* __restrict__ Mf,
                         ushort* __restrict__ Mb) {
    const int i = (blockIdx.x * 256 + threadIdx.x) * 8;
    const float4 v0 = *(const float4*)&Mf[i];
    const float4 v1 = *(const float4*)&Mf[i + 4];
    ushort u[8];
    u[0] = f2bf_rne(v0.x); u[1] = f2bf_rne(v0.y);
    u[2] = f2bf_rne(v0.z); u[3] = f2bf_rne(v0.w);
    u[4] = f2bf_rne(v1.x); u[5] = f2bf_rne(v1.y);
    u[6] = f2bf_rne(v1.z); u[7] = f2bf_rne(v1.w);
    *(uint4*)&Mb[i] = *(uint4*)u;
}

// ---------------------------------------------------------------------------
// GEMM2: out[n][f] (+)= dv_inv[n] * sum_e H[n][e] * MT[f][e]
//   No LDS. A-frag (H row) = 2 contiguous dwordx4 loads; B-frag (MT) 16-B
//   vector loads (L2-resident).
// Grid (N/64, KSPLIT); wave -> 16 n-rows x 128 f.
// ---------------------------------------------------------------------------
__global__ __launch_bounds__(256, 4) void k_gemm2(
        const float* __restrict__ Hg,        // [N][E] fp32
        const ushort* __restrict__ MTb,      // [F][E] bf16
        const float* __restrict__ dv_inv,    // [N]
        float* __restrict__ Out) {           // [N][F] fp32 (atomic)
    const int t    = threadIdx.x;
    const int wave = t >> 6;
    const int lane = t & 63;
    const int mm   = lane & 15;
    const int quad = lane >> 4;
    const int nw   = blockIdx.x * 64 + wave * 16;   // wave's 16 n-rows
    const int kb   = blockIdx.y * KEXT;

    f32x4 acc[8];
    #pragma unroll
    for (int fs = 0; fs < 8; ++fs) acc[fs] = (f32x4){0.f, 0.f, 0.f, 0.f};

    const float* hrow = Hg + (size_t)(nw + mm) * E;   // this lane's n-row

    for (int ch = 0; ch < NCH; ++ch) {
        const int kg = kb + ch * BK;
        // H row fragments: 8 contiguous fp32 at e = kg + kk*32 + quad*8
        float4 hv[2][2];
        #pragma unroll
        for (int kk = 0; kk < 2; ++kk) {
            const int ko = kg + kk * 32 + quad * 8;
            hv[kk][0] = *(const float4*)&hrow[ko];
            hv[kk][1] = *(const float4*)&hrow[ko + 4];
        }
        // MT fragments (both kk)
        bf16x8 bf[2][8];
        #pragma unroll
        for (int kk = 0; kk < 2; ++kk) {
            const int ko = kg + kk * 32 + quad * 8;
            #pragma unroll
            for (int fs = 0; fs < 8; ++fs)
                bf[kk][fs] = *(const bf16x8*)&MTb[(size_t)(fs * 16 + mm) * E + ko];
        }
        #pragma unroll
        for (int kk = 0; kk < 2; ++kk) {
            bf16x8 ha;
            ha[0] = f2bf_trunc(hv[kk][0].x); ha[1] = f2bf_trunc(hv[kk][0].y);
            ha[2] = f2bf_trunc(hv[kk][0].z); ha[3] = f2bf_trunc(hv[kk][0].w);
            ha[4] = f2bf_trunc(hv[kk][1].x); ha[5] = f2bf_trunc(hv[kk][1].y);
            ha[6] = f2bf_trunc(hv[kk][1].z); ha[7] = f2bf_trunc(hv[kk][1].w);
            #pragma unroll
            for (int fs = 0; fs < 8; ++fs)
                acc[fs] = __builtin_amdgcn_mfma_f32_16x16x32_bf16(
                              ha, bf[kk][fs], acc[fs], 0, 0, 0);
        }
    }
    // Epilogue: D row = n (quad*4 + r), col = f (fs*16 + mm); scale dv_inv[n]
    const int rowb = nw + quad * 4;
    const float4 rs = *(const float4*)&dv_inv[rowb];
    const float rsa[4] = {rs.x, rs.y, rs.z, rs.w};
    #pragma unroll
    for (int fs = 0; fs < 8; ++fs) {
        const int col = fs * 16 + mm;
        #pragma unroll
        for (int r = 0; r < 4; ++r)
            atomicAdd(&Out[(size_t)(rowb + r) * F + col], acc[fs][r] * rsa[r]);
    }
}

// ---------------------------------------------------------------------------
extern "C" void kernel_launch(void* const* d_in, const int* in_sizes, int n_in,
                              void* d_out, int out_size, void* d_ws, size_t ws_size,
                              hipStream_t stream) {
    const float* X  = (const float*)d_in[0];   // [N,128]
    const float* H  = (const float*)d_in[1];   // [N,E] fp32 (binary)
    const float* Dv = (const float*)d_in[2];   // [N,N]
    const float* De = (const float*)d_in[3];   // [E,E]
    const float* W  = (const float*)d_in[4];   // [128,128]
    float* out = (float*)d_out;                // [N,128]
    char* ws = (char*)d_ws;

    // workspace layout (~4.03 MB)
    float*  MTf    = (float*)ws;                                   // 2 MB  [f][e] fp32
    ushort* MTbf   = (ushort*)(ws + (size_t)2 * 1024 * 1024);      // 1 MB  [f][e] bf16
    ushort* thetaT = (ushort*)(ws + (size_t)3 * 1024 * 1024);      // 1 MB  [f][n] bf16
    float*  dv_inv = (float*)(ws + (size_t)4 * 1024 * 1024);       // 16 KB
    float*  de_inv = dv_inv + N;                                   // 16 KB

    hipMemsetAsync(MTf, 0, (size_t)F * E * sizeof(float), stream);
    hipMemsetAsync(out, 0, (size_t)N * F * sizeof(float), stream);

    k_recip_diag<<<dim3(N / 256), dim3(256), 0, stream>>>(Dv, De, dv_inv, de_inv);
    k_theta_t<<<dim3(N / 8), dim3(128), 0, stream>>>(X, W, thetaT);
    // GEMM1': MT[f][e] = de_inv[e] * sum_n thetaT[f][n] * H[n][e]
    k_gemm1<<<dim3(E / 64, KSPLIT), dim3(256), 0, stream>>>(H, thetaT, de_inv, MTf);
    k_castMT<<<dim3(F * E / 8 / 256), dim3(256), 0, stream>>>(MTf, MTbf);
    // GEMM2: out[n][f] = dv_inv[n] * sum_e H[n][e] * MT[f][e]
    k_gemm2<<<dim3(N / 64, KSPLIT), dim3(256), 0, stream>>>(H, MTbf, dv_inv, out);
}

// Round 7
// 289.132 us; speedup vs baseline: 1.0025x; 1.0025x over previous
//
#include <hip/hip_runtime.h>

// Problem constants
constexpr int N = 4096;   // nodes
constexpr int E = 4096;   // hyperedges
constexpr int F = 128;

// K-split: each block covers 256 k; grid (4096/64, KSPLIT); atomics combine.
constexpr int KSPLIT = 16;
constexpr int KEXT   = 4096 / KSPLIT;   // 256 k per block
constexpr int BK     = 64;              // k per chunk
constexpr int NCH    = KEXT / BK;       // 4 chunks

typedef __attribute__((ext_vector_type(8))) short bf16x8;
typedef __attribute__((ext_vector_type(4))) float f32x4;

__device__ __forceinline__ ushort f2bf_rne(float x) {
    union { float f; unsigned u; } v; v.f = x;
    return (ushort)((v.u + 0x7FFFu + ((v.u >> 16) & 1u)) >> 16);
}
// H is exactly {0,1}: truncation is exact.
__device__ __forceinline__ short f2bf_trunc(float x) {
    return (short)(ushort)(__float_as_uint(x) >> 16);
}

// ---------------------------------------------------------------------------
// reciprocal of the diagonals of D_v / D_e
// ---------------------------------------------------------------------------
__global__ void k_recip_diag(const float* __restrict__ Dv,
                             const float* __restrict__ De,
                             float* __restrict__ dv_inv,
                             float* __restrict__ de_inv) {
    int i = blockIdx.x * blockDim.x + threadIdx.x;
    if (i < N) dv_inv[i] = 1.0f / Dv[(size_t)i * (N + 1)];
    if (i < E) de_inv[i] = 1.0f / De[(size_t)i * (E + 1)];
}

// ---------------------------------------------------------------------------
// thetaT[f][n] = bf16( (X@W)[n][f] )   — [128][4096] bf16
// ---------------------------------------------------------------------------
__global__ void k_theta_t(const float* __restrict__ X,
                          const float* __restrict__ W,
                          ushort* __restrict__ thetaT) {
    __shared__ float Xs[8][F];
    const int r0 = blockIdx.x * 8;
    const int t  = threadIdx.x;  // 0..127 = f
    #pragma unroll
    for (int i = 0; i < 8; ++i)
        Xs[i][t] = X[(size_t)(r0 + i) * F + t];
    __syncthreads();
    float acc[8];
    #pragma unroll
    for (int i = 0; i < 8; ++i) acc[i] = 0.0f;
    for (int k = 0; k < F; ++k) {
        const float w = W[k * F + t];
        #pragma unroll
        for (int i = 0; i < 8; ++i) acc[i] += Xs[i][k] * w;
    }
    ushort u[8];
    #pragma unroll
    for (int i = 0; i < 8; ++i) u[i] = f2bf_rne(acc[i]);
    *(uint4*)&thetaT[(size_t)t * N + r0] = *(uint4*)u;
}

// ---------------------------------------------------------------------------
// GEMM1': MT[f][e] (+)= de_inv[e] * sum_n thetaT[f][n] * H[n][e]
//   No LDS. Explicit register double-buffer on the H (HBM-cold) operand:
//   chunk ch+1's 16 strided dword loads are issued before chunk ch's MFMAs,
//   and the 16 thetaT 16-B loads for chunk ch are issued as one burst.
//   The pf/cur registers are live across the MFMA phase -> allocator must
//   keep ~20 KB/wave of loads in flight -> HBM-bound, not latency-bound.
// Grid (E/64, KSPLIT); 256 thr = 4 waves; wave -> 16 e-cols x 128 f-rows.
// ---------------------------------------------------------------------------
__global__ __launch_bounds__(256, 2) void k_gemm1(
        const float* __restrict__ Hg,        // [N][E] fp32
        const ushort* __restrict__ thT,      // [F][N] bf16
        const float* __restrict__ de_inv,    // [E]
        float* __restrict__ MTf) {           // [F][E] fp32 (atomic)
    const int t    = threadIdx.x;
    const int wave = t >> 6;
    const int lane = t & 63;
    const int mm   = lane & 15;
    const int quad = lane >> 4;
    const int ew   = blockIdx.x * 64 + wave * 16;   // wave's 16 e-columns
    const int kb   = blockIdx.y * KEXT;

    f32x4 acc[8];
    #pragma unroll
    for (int ft = 0; ft < 8; ++ft) acc[ft] = (f32x4){0.f, 0.f, 0.f, 0.f};

    const float* hcol = Hg + ew + mm;               // this lane's e-column

    float  hv[2][16];    // [buf][kk*8+j]  H^T fragments (strided dwords)
    bf16x8 af[16];       // [kk*8+ft]      thetaT fragments (one chunk)

    // issue all 16 H loads for chunk ch into buffer b
    auto loadH = [&](int ch, float* hb) {
        const int kg = kb + ch * BK;
        #pragma unroll
        for (int kk = 0; kk < 2; ++kk) {
            const int nbase = kg + kk * 32 + quad * 8;
            #pragma unroll
            for (int j = 0; j < 8; ++j)
                hb[kk * 8 + j] = hcol[(size_t)(nbase + j) * E];
        }
    };

    loadH(0, hv[0]);
    #pragma unroll
    for (int ch = 0; ch < NCH; ++ch) {
        const int nb = ch & 1, pf = nb ^ 1;
        // 1) prefetch next chunk's H (HBM) — issued before anything waits
        if (ch + 1 < NCH) loadH(ch + 1, hv[pf]);
        // 2) burst-load this chunk's thetaT fragments (L2-resident)
        const int kg = kb + ch * BK;
        #pragma unroll
        for (int kk = 0; kk < 2; ++kk) {
            const int ko = kg + kk * 32 + quad * 8;
            #pragma unroll
            for (int ft = 0; ft < 8; ++ft)
                af[kk * 8 + ft] = *(const bf16x8*)&thT[(size_t)(ft * 16 + mm) * N + ko];
        }
        // 3) convert + MFMA on current buffer
        #pragma unroll
        for (int kk = 0; kk < 2; ++kk) {
            bf16x8 hb;
            #pragma unroll
            for (int j = 0; j < 8; ++j) hb[j] = f2bf_trunc(hv[nb][kk * 8 + j]);
            #pragma unroll
            for (int ft = 0; ft < 8; ++ft)
                acc[ft] = __builtin_amdgcn_mfma_f32_16x16x32_bf16(
                              af[kk * 8 + ft], hb, acc[ft], 0, 0, 0);
        }
    }
    // Epilogue: D row = f (ft*16 + quad*4 + r), col = e (mm); scale de_inv[e]
    const float s = de_inv[ew + mm];
    #pragma unroll
    for (int ft = 0; ft < 8; ++ft) {
        const int row = ft * 16 + quad * 4;
        #pragma unroll
        for (int r = 0; r < 4; ++r)
            atomicAdd(&MTf[(size_t)(row + r) * E + ew + mm], acc[ft][r] * s);
    }
}

// ---------------------------------------------------------------------------
// streaming cast: MTb[f][e] = bf16(MTf[f][e])
// ---------------------------------------------------------------------------
__global__ void k_castMT(const float* __restrict__ Mf,
                         ushort* __restrict__ Mb) {
    const int i = (blockIdx.x * 256 + threadIdx.x) * 8;
    const float4 v0 = *(const float4*)&Mf[i];
    const float4 v1 = *(const float4*)&Mf[i + 4];
    ushort u[8];
    u[0] = f2bf_rne(v0.x); u[1] = f2bf_rne(v0.y);
    u[2] = f2bf_rne(v0.z); u[3] = f2bf_rne(v0.w);
    u[4] = f2bf_rne(v1.x); u[5] = f2bf_rne(v1.y);
    u[6] = f2bf_rne(v1.z); u[7] = f2bf_rne(v1.w);
    *(uint4*)&Mb[i] = *(uint4*)u;
}

// ---------------------------------------------------------------------------
// GEMM2: out[n][f] (+)= dv_inv[n] * sum_e H[n][e] * MT[f][e]
//   Same register double-buffer pipeline; H rows are contiguous dwordx4.
// Grid (N/64, KSPLIT); wave -> 16 n-rows x 128 f.
// ---------------------------------------------------------------------------
__global__ __launch_bounds__(256, 2) void k_gemm2(
        const float* __restrict__ Hg,        // [N][E] fp32
        const ushort* __restrict__ MTb,      // [F][E] bf16
        const float* __restrict__ dv_inv,    // [N]
        float* __restrict__ Out) {           // [N][F] fp32 (atomic)
    const int t    = threadIdx.x;
    const int wave = t >> 6;
    const int lane = t & 63;
    const int mm   = lane & 15;
    const int quad = lane >> 4;
    const int nw   = blockIdx.x * 64 + wave * 16;   // wave's 16 n-rows
    const int kb   = blockIdx.y * KEXT;

    f32x4 acc[8];
    #pragma unroll
    for (int fs = 0; fs < 8; ++fs) acc[fs] = (f32x4){0.f, 0.f, 0.f, 0.f};

    const float* hrow = Hg + (size_t)(nw + mm) * E;   // this lane's n-row

    float4 hv[2][4];     // [buf][kk*2+half]  H row fragments
    bf16x8 bf[16];       // [kk*8+fs]         MT fragments (one chunk)

    auto loadH = [&](int ch, float4* hb) {
        const int kg = kb + ch * BK;
        #pragma unroll
        for (int kk = 0; kk < 2; ++kk) {
            const int ko = kg + kk * 32 + quad * 8;
            hb[kk * 2 + 0] = *(const float4*)&hrow[ko];
            hb[kk * 2 + 1] = *(const float4*)&hrow[ko + 4];
        }
    };

    loadH(0, hv[0]);
    #pragma unroll
    for (int ch = 0; ch < NCH; ++ch) {
        const int nb = ch & 1, pf = nb ^ 1;
        if (ch + 1 < NCH) loadH(ch + 1, hv[pf]);
        const int kg = kb + ch * BK;
        #pragma unroll
        for (int kk = 0; kk < 2; ++kk) {
            const int ko = kg + kk * 32 + quad * 8;
            #pragma unroll
            for (int fs = 0; fs < 8; ++fs)
                bf[kk * 8 + fs] = *(const bf16x8*)&MTb[(size_t)(fs * 16 + mm) * E + ko];
        }
        #pragma unroll
        for (int kk = 0; kk < 2; ++kk) {
            const float4 v0 = hv[nb][kk * 2 + 0];
            const float4 v1 = hv[nb][kk * 2 + 1];
            bf16x8 ha;
            ha[0] = f2bf_trunc(v0.x); ha[1] = f2bf_trunc(v0.y);
            ha[2] = f2bf_trunc(v0.z); ha[3] = f2bf_trunc(v0.w);
            ha[4] = f2bf_trunc(v1.x); ha[5] = f2bf_trunc(v1.y);
            ha[6] = f2bf_trunc(v1.z); ha[7] = f2bf_trunc(v1.w);
            #pragma unroll
            for (int fs = 0; fs < 8; ++fs)
                acc[fs] = __builtin_amdgcn_mfma_f32_16x16x32_bf16(
                              ha, bf[kk * 8 + fs], acc[fs], 0, 0, 0);
        }
    }
    // Epilogue: D row = n (quad*4 + r), col = f (fs*16 + mm); scale dv_inv[n]
    const int rowb = nw + quad * 4;
    const float4 rs = *(const float4*)&dv_inv[rowb];
    const float rsa[4] = {rs.x, rs.y, rs.z, rs.w};
    #pragma unroll
    for (int fs = 0; fs < 8; ++fs) {
        const int col = fs * 16 + mm;
        #pragma unroll
        for (int r = 0; r < 4; ++r)
            atomicAdd(&Out[(size_t)(rowb + r) * F + col], acc[fs][r] * rsa[r]);
    }
}

// ---------------------------------------------------------------------------
extern "C" void kernel_launch(void* const* d_in, const int* in_sizes, int n_in,
                              void* d_out, int out_size, void* d_ws, size_t ws_size,
                              hipStream_t stream) {
    const float* X  = (const float*)d_in[0];   // [N,128]
    const float* H  = (const float*)d_in[1];   // [N,E] fp32 (binary)
    const float* Dv = (const float*)d_in[2];   // [N,N]
    const float* De = (const float*)d_in[3];   // [E,E]
    const float* W  = (const float*)d_in[4];   // [128,128]
    float* out = (float*)d_out;                // [N,128]
    char* ws = (char*)d_ws;

    // workspace layout (~4.03 MB)
    float*  MTf    = (float*)ws;                                   // 2 MB  [f][e] fp32
    ushort* MTbf   = (ushort*)(ws + (size_t)2 * 1024 * 1024);      // 1 MB  [f][e] bf16
    ushort* thetaT = (ushort*)(ws + (size_t)3 * 1024 * 1024);      // 1 MB  [f][n] bf16
    float*  dv_inv = (float*)(ws + (size_t)4 * 1024 * 1024);       // 16 KB
    float*  de_inv = dv_inv + N;                                   // 16 KB

    hipMemsetAsync(MTf, 0, (size_t)F * E * sizeof(float), stream);
    hipMemsetAsync(out, 0, (size_t)N * F * sizeof(float), stream);

    k_recip_diag<<<dim3(N / 256), dim3(256), 0, stream>>>(Dv, De, dv_inv, de_inv);
    k_theta_t<<<dim3(N / 8), dim3(128), 0, stream>>>(X, W, thetaT);
    // GEMM1': MT[f][e] = de_inv[e] * sum_n thetaT[f][n] * H[n][e]
    k_gemm1<<<dim3(E / 64, KSPLIT), dim3(256), 0, stream>>>(H, thetaT, de_inv, MTf);
    k_castMT<<<dim3(F * E / 8 / 256), dim3(256), 0, stream>>>(MTf, MTbf);
    // GEMM2: out[n][f] = dv_inv[n] * sum_e H[n][e] * MT[f][e]
    k_gemm2<<<dim3(N / 64, KSPLIT), dim3(256), 0, stream>>>(H, MTbf, dv_inv, out);
}